// Round 8
// baseline (1165.260 us; speedup 1.0000x reference)
//
#include <hip/hip_runtime.h>

#define NB 16
#define NPTS 4096
#define NC 64
#define NS 1024
#define NK 32

// ---------------------------------------------------------------------------
// FPS: one block per batch, 256 threads (4 waves), 16 points/lane in regs.
// Selection semantics identical to R5/R6/R7 (verified): max dist, lowest
// index on ties; distance arithmetic bit-identical. R8: single (val,idx)
// lane tree with static tie-break; single fused u64-key DPP wave chain.
// ---------------------------------------------------------------------------
#define DPP_ROR_I(x, N) __builtin_amdgcn_update_dpp(0, (int)(x), 0x120 + (N), 0xf, 0xf, false)

__global__ __launch_bounds__(256) void fps_kernel(const float* __restrict__ xyz,
                                                  float* __restrict__ out_xyz) {
    __shared__ float4 pts4[NPTS];
    __shared__ float hx[NS], hy[NS], hz[NS];
    __shared__ __align__(16) unsigned long long wkey[2][4];

    const int b = blockIdx.x;
    const int t = threadIdx.x;
    const int wv = t >> 6;
    const int lane = t & 63;

    const float* xb = xyz + (size_t)b * NPTS * 3;
    for (int i = t; i < NPTS; i += 256) {
        pts4[i] = make_float4(xb[3 * i], xb[3 * i + 1], xb[3 * i + 2], 0.0f);
    }
    __syncthreads();

    float px[16], py[16], pz[16], dm[16];
#pragma unroll
    for (int j = 0; j < 16; ++j) {
        const float4 p = pts4[t + j * 256];
        px[j] = p.x; py[j] = p.y; pz[j] = p.z;
        dm[j] = 1e10f;
    }

    const float4 c0 = pts4[0];
    float cx = c0.x, cy = c0.y, cz = c0.z;

    for (int s = 0; s < NS; ++s) {
        if (t == 0) { hx[s] = cx; hy[s] = cy; hz[s] = cz; }

        // update min-dists (bit-identical arithmetic)
#pragma unroll
        for (int j = 0; j < 16; ++j) {
            const float dx = __fsub_rn(px[j], cx);
            const float dy = __fsub_rn(py[j], cy);
            const float dz = __fsub_rn(pz[j], cz);
            const float d = __fadd_rn(__fadd_rn(__fmul_rn(dx, dx), __fmul_rn(dy, dy)),
                                      __fmul_rn(dz, dz));
            dm[j] = fminf(dm[j], d);
        }

        // single (val, idx) lane tree, depth 4. At every level the left
        // operand has the strictly lower global index, so (b > a) ? b : a
        // == max value with lowest index on ties.
        float v8[8], v4[4], v2[2];
        unsigned i8[8], i4[4], i2[2];
#pragma unroll
        for (int j = 0; j < 8; ++j) {
            const bool w = dm[2 * j + 1] > dm[2 * j];
            v8[j] = w ? dm[2 * j + 1] : dm[2 * j];
            i8[j] = (unsigned)(t + (w ? (2 * j + 1) : (2 * j)) * 256);
        }
#pragma unroll
        for (int j = 0; j < 4; ++j) {
            const bool w = v8[2 * j + 1] > v8[2 * j];
            v4[j] = w ? v8[2 * j + 1] : v8[2 * j];
            i4[j] = w ? i8[2 * j + 1] : i8[2 * j];
        }
#pragma unroll
        for (int j = 0; j < 2; ++j) {
            const bool w = v4[2 * j + 1] > v4[2 * j];
            v2[j] = w ? v4[2 * j + 1] : v4[2 * j];
            i2[j] = w ? i4[2 * j + 1] : i4[2 * j];
        }
        const bool wl = v2[1] > v2[0];
        const float mv = wl ? v2[1] : v2[0];
        const unsigned mi = wl ? i2[1] : i2[0];

        // fused u64-key DPP row all-reduce (key = dist_bits<<32 | ~idx:
        // greater key == greater dist, ties -> lower idx)
        unsigned kh = __float_as_uint(mv);
        unsigned kl = ~mi;
#pragma unroll
        for (int st = 1; st < 16; st <<= 1) {
            unsigned oh, ol;
            if (st == 1)      { oh = (unsigned)DPP_ROR_I(kh, 1); ol = (unsigned)DPP_ROR_I(kl, 1); }
            else if (st == 2) { oh = (unsigned)DPP_ROR_I(kh, 2); ol = (unsigned)DPP_ROR_I(kl, 2); }
            else if (st == 4) { oh = (unsigned)DPP_ROR_I(kh, 4); ol = (unsigned)DPP_ROR_I(kl, 4); }
            else              { oh = (unsigned)DPP_ROR_I(kh, 8); ol = (unsigned)DPP_ROR_I(kl, 8); }
            const unsigned long long ko = ((unsigned long long)oh << 32) | ol;
            const unsigned long long kk = ((unsigned long long)kh << 32) | kl;
            const bool sw = ko > kk;
            kh = sw ? oh : kh;
            kl = sw ? ol : kl;
        }

        // cross-row merge via readlane (rows 0,16,32,48), scalar max tree
        const unsigned long long k0 =
            ((unsigned long long)(unsigned)__builtin_amdgcn_readlane((int)kh, 0) << 32) |
            (unsigned)__builtin_amdgcn_readlane((int)kl, 0);
        const unsigned long long k1 =
            ((unsigned long long)(unsigned)__builtin_amdgcn_readlane((int)kh, 16) << 32) |
            (unsigned)__builtin_amdgcn_readlane((int)kl, 16);
        const unsigned long long k2 =
            ((unsigned long long)(unsigned)__builtin_amdgcn_readlane((int)kh, 32) << 32) |
            (unsigned)__builtin_amdgcn_readlane((int)kl, 32);
        const unsigned long long k3 =
            ((unsigned long long)(unsigned)__builtin_amdgcn_readlane((int)kh, 48) << 32) |
            (unsigned)__builtin_amdgcn_readlane((int)kl, 48);
        const unsigned long long ka = k0 > k1 ? k0 : k1;
        const unsigned long long kb = k2 > k3 ? k2 : k3;
        const unsigned long long kw = ka > kb ? ka : kb;

        // cross-wave merge via double-buffered LDS keys (one barrier/iter)
        if (lane == 0) wkey[s & 1][wv] = kw;
        __syncthreads();
        const ulonglong2* wkp = (const ulonglong2*)&wkey[s & 1][0];
        const ulonglong2 p01 = wkp[0];
        const ulonglong2 p23 = wkp[1];
        const unsigned long long ma = p01.x > p01.y ? p01.x : p01.y;
        const unsigned long long mb = p23.x > p23.y ? p23.x : p23.y;
        const unsigned long long kf = ma > mb ? ma : mb;

        const int wi = (int)(~(unsigned)kf);
        const float4 cc = pts4[wi];
        cx = cc.x; cy = cc.y; cz = cc.z;
    }

    // flush centroid history to global, coalesced
    __syncthreads();
    float* ob = out_xyz + (size_t)b * NS * 3;
#pragma unroll
    for (int r2 = 0; r2 < 12; ++r2) {
        const int f = t + r2 * 256;
        const int i = f / 3;
        const int cmp = f - 3 * i;
        const float v = (cmp == 0) ? hx[i] : ((cmp == 1) ? hy[i] : hz[i]);
        ob[f] = v;
    }
}

// ---------------------------------------------------------------------------
// KNN: one wave per query. fp32 expanded-form distances replicating the
// reference's rounding: dot as an FMA chain, d = (qsq - 2*dot) + psq,
// qsq/psq sequential no-FMA.  [R4-verified exact]
// Per-lane sorted top-4 + lazy refill; 32 rounds of wave argmin.
// ---------------------------------------------------------------------------
#define KNN_INF 3.0e38f

__global__ __launch_bounds__(1024) void knn_kernel(const float* __restrict__ xyz,
                                                   const float* __restrict__ newxyz,
                                                   unsigned short* __restrict__ knn) {
    __shared__ float4 pts[NPTS];

    const int b = blockIdx.x >> 6;
    const int t = threadIdx.x;
    const float* xb = xyz + (size_t)b * NPTS * 3;
    for (int i = t; i < NPTS; i += 1024) {
        const float x = xb[3 * i], y = xb[3 * i + 1], z = xb[3 * i + 2];
        const float ps = __fadd_rn(__fadd_rn(__fmul_rn(x, x), __fmul_rn(y, y)), __fmul_rn(z, z));
        pts[i] = make_float4(x, y, z, ps);
    }
    __syncthreads();

    const int lane = t & 63;
    const int wv = t >> 6;
    const int s = ((blockIdx.x & 63) << 4) + wv;

    const float* q = newxyz + ((size_t)b * NS + s) * 3;
    const float qx = q[0], qy = q[1], qz = q[2];
    const float qs = __fadd_rn(__fadd_rn(__fmul_rn(qx, qx), __fmul_rn(qy, qy)), __fmul_rn(qz, qz));

    float v0 = KNN_INF, v1 = KNN_INF, v2 = KNN_INF, v3 = KNN_INF;
    int i0 = 0, i1 = 0, i2 = 0, i3 = 0;
    unsigned long long rem = 0ull;

#pragma unroll 4
    for (int j = 0; j < 64; ++j) {
        const float4 p = pts[j * 64 + lane];
        const float dot = __fmaf_rn(qz, p.z, __fmaf_rn(qy, p.y, __fmul_rn(qx, p.x)));
        const float d = __fadd_rn(__fsub_rn(qs, __fadd_rn(dot, dot)), p.w);
        const int gi = j * 64 + lane;
        const bool c0 = d < v0, c1 = d < v1, c2 = d < v2, c3 = d < v3;
        v3 = c3 ? (c2 ? v2 : d) : v3;  i3 = c3 ? (c2 ? i2 : gi) : i3;
        v2 = c2 ? (c1 ? v1 : d) : v2;  i2 = c2 ? (c1 ? i1 : gi) : i2;
        v1 = c1 ? (c0 ? v0 : d) : v1;  i1 = c1 ? (c0 ? i0 : gi) : i1;
        v0 = c0 ? d : v0;              i0 = c0 ? gi : i0;
    }

    int kidx = 0;
#pragma unroll 1
    for (int r = 0; r < NK; ++r) {
        float bv = v0;
        int bi = i0;
#pragma unroll
        for (int m = 1; m < 64; m <<= 1) {
            const float ov = __shfl_xor(bv, m);
            const int   oi = __shfl_xor(bi, m);
            if (ov < bv || (ov == bv && oi < bi)) { bv = ov; bi = oi; }
        }
        if (lane == r) kidx = bi;
        if ((bi & 63) == lane) {
            v0 = v1; i0 = i1;
            v1 = v2; i1 = i2;
            v2 = v3; i2 = i3;
            v3 = KNN_INF;
            rem |= 1ull << (bi >> 6);
            if (v0 >= 1e37f) {
                v0 = v1 = v2 = v3 = KNN_INF;
#pragma unroll 1
                for (int j = 0; j < 64; ++j) {
                    if (!((rem >> j) & 1ull)) {
                        const float4 p = pts[j * 64 + lane];
                        const float dot = __fmaf_rn(qz, p.z, __fmaf_rn(qy, p.y, __fmul_rn(qx, p.x)));
                        const float d = __fadd_rn(__fsub_rn(qs, __fadd_rn(dot, dot)), p.w);
                        const int gi = j * 64 + lane;
                        const bool c0 = d < v0, c1 = d < v1, c2 = d < v2, c3 = d < v3;
                        v3 = c3 ? (c2 ? v2 : d) : v3;  i3 = c3 ? (c2 ? i2 : gi) : i3;
                        v2 = c2 ? (c1 ? v1 : d) : v2;  i2 = c2 ? (c1 ? i1 : gi) : i2;
                        v1 = c1 ? (c0 ? v0 : d) : v1;  i1 = c1 ? (c0 ? i0 : gi) : i1;
                        v0 = c0 ? d : v0;              i0 = c0 ? gi : i0;
                    }
                }
            }
        }
    }

    if (lane < NK) knn[(((size_t)b * NS + s) << 5) + lane] = (unsigned short)kidx;
}

// ---------------------------------------------------------------------------
// Gather + 3-layer 1x1-conv MLP + max-pool over K.
// One lane per (group, neighbor) row; 2 groups per wave; 8 groups per block.
// ---------------------------------------------------------------------------
__global__ __launch_bounds__(256) void mlp_kernel(const float* __restrict__ xyz,
                                                  const float* __restrict__ points,
                                                  const float* __restrict__ newxyz,
                                                  const unsigned short* __restrict__ knn,
                                                  const float* __restrict__ w0, const float* __restrict__ b0,
                                                  const float* __restrict__ w1, const float* __restrict__ b1,
                                                  const float* __restrict__ w2, const float* __restrict__ b2,
                                                  float* __restrict__ out) {
    __shared__ float act[67][256];

    const int t = threadIdx.x;
    const int lane = t & 63;
    const int g = blockIdx.x * 8 + ((t >> 6) << 1) + ((lane >> 5) & 1);
    const int b = g >> 10;
    const int k = lane & 31;

    const int idx = knn[((size_t)g << 5) + k];
    const float* nq = newxyz + (size_t)g * 3;
    const float* pp = xyz + ((size_t)b * NPTS + idx) * 3;
    act[0][t] = pp[0] - nq[0];
    act[1][t] = pp[1] - nq[1];
    act[2][t] = pp[2] - nq[2];
    const float4* pr = (const float4*)(points + (((size_t)b * NPTS + idx) << 6));
#pragma unroll
    for (int j = 0; j < 16; ++j) {
        const float4 v = pr[j];
        act[3 + 4 * j][t] = v.x;
        act[4 + 4 * j][t] = v.y;
        act[5 + 4 * j][t] = v.z;
        act[6 + 4 * j][t] = v.w;
    }

    float h[128];

    // layer 1: 67 -> 64
#pragma unroll
    for (int f = 0; f < 64; ++f) h[f] = b0[f];
#pragma unroll 1
    for (int i = 0; i < 67; ++i) {
        const float xi = act[i][t];
        const float* wr = w0 + (i << 6);
#pragma unroll
        for (int f = 0; f < 64; ++f) h[f] = fmaf(xi, wr[f], h[f]);
    }
#pragma unroll
    for (int f = 0; f < 64; ++f) act[f][t] = fmaxf(h[f], 0.0f);

    // layer 2: 64 -> 64
#pragma unroll
    for (int f = 0; f < 64; ++f) h[f] = b1[f];
#pragma unroll 1
    for (int i = 0; i < 64; ++i) {
        const float xi = act[i][t];
        const float* wr = w1 + (i << 6);
#pragma unroll
        for (int f = 0; f < 64; ++f) h[f] = fmaf(xi, wr[f], h[f]);
    }
#pragma unroll
    for (int f = 0; f < 64; ++f) act[f][t] = fmaxf(h[f], 0.0f);

    // layer 3: 64 -> 128
#pragma unroll
    for (int f = 0; f < 128; ++f) h[f] = b2[f];
#pragma unroll 1
    for (int i = 0; i < 64; ++i) {
        const float xi = act[i][t];
        const float* wr = w2 + (i << 7);
#pragma unroll
        for (int f = 0; f < 128; ++f) h[f] = fmaf(xi, wr[f], h[f]);
    }
#pragma unroll
    for (int f = 0; f < 128; ++f) h[f] = fmaxf(h[f], 0.0f);

    // butterfly reduce-scatter max over the 32 lanes of each half-wave.
    float t64[64];
#pragma unroll
    for (int c = 0; c < 64; ++c) {
        const bool hi = (lane & 16);
        const float kept = hi ? h[c + 64] : h[c];
        const float snt  = hi ? h[c] : h[c + 64];
        t64[c] = fmaxf(kept, __shfl_xor(snt, 16));
    }
    float t32a[32];
#pragma unroll
    for (int c = 0; c < 32; ++c) {
        const bool hi = (lane & 8);
        const float kept = hi ? t64[c + 32] : t64[c];
        const float snt  = hi ? t64[c] : t64[c + 32];
        t32a[c] = fmaxf(kept, __shfl_xor(snt, 8));
    }
    float t16a[16];
#pragma unroll
    for (int c = 0; c < 16; ++c) {
        const bool hi = (lane & 4);
        const float kept = hi ? t32a[c + 16] : t32a[c];
        const float snt  = hi ? t32a[c] : t32a[c + 16];
        t16a[c] = fmaxf(kept, __shfl_xor(snt, 4));
    }
    float t8a[8];
#pragma unroll
    for (int c = 0; c < 8; ++c) {
        const bool hi = (lane & 2);
        const float kept = hi ? t16a[c + 8] : t16a[c];
        const float snt  = hi ? t16a[c] : t16a[c + 8];
        t8a[c] = fmaxf(kept, __shfl_xor(snt, 2));
    }
    float t4a[4];
#pragma unroll
    for (int c = 0; c < 4; ++c) {
        const bool hi = (lane & 1);
        const float kept = hi ? t8a[c + 4] : t8a[c];
        const float snt  = hi ? t8a[c] : t8a[c + 4];
        t4a[c] = fmaxf(kept, __shfl_xor(snt, 1));
    }

    float* op = out + (size_t)g * 128 + ((lane & 31) << 2);
    *(float4*)op = make_float4(t4a[0], t4a[1], t4a[2], t4a[3]);
}

extern "C" void kernel_launch(void* const* d_in, const int* in_sizes, int n_in,
                              void* d_out, int out_size, void* d_ws, size_t ws_size,
                              hipStream_t stream) {
    const float* xyz    = (const float*)d_in[0];
    const float* points = (const float*)d_in[1];
    const float* w0 = (const float*)d_in[2];
    const float* b0 = (const float*)d_in[3];
    const float* w1 = (const float*)d_in[4];
    const float* b1 = (const float*)d_in[5];
    const float* w2 = (const float*)d_in[6];
    const float* b2 = (const float*)d_in[7];

    float* out = (float*)d_out;
    float* newxyz = out;                          // (B, S, 3)
    float* newpts = out + (size_t)NB * NS * 3;    // (B, S, 128)
    unsigned short* knn = (unsigned short*)d_ws;  // (B, S, K) u16, 1 MB

    fps_kernel<<<NB, 256, 0, stream>>>(xyz, newxyz);
    knn_kernel<<<NB * (NS / 16), 1024, 0, stream>>>(xyz, newxyz, knn);
    mlp_kernel<<<(NB * NS) / 8, 256, 0, stream>>>(xyz, points, newxyz, knn,
                                                  w0, b0, w1, b1, w2, b2, newpts);
}

// Round 9
// 960.778 us; speedup vs baseline: 1.2128x; 1.2128x over previous
//
#include <hip/hip_runtime.h>

#define NB 16
#define NPTS 4096
#define NC 64
#define NS 1024
#define NK 32

typedef float v2f __attribute__((ext_vector_type(2)));

// ---------------------------------------------------------------------------
// FPS: one block per batch, 256 threads (4 waves), 16 points/lane in regs.
// Structure identical to R6 (the 693 us verified optimum): centroid history
// in LDS, depth-4 fmax tree + eq/min-u32 tree, two-pass f32-max / u32-min
// DPP wave reduce, single u64-key cross-wave LDS merge.
// R9 change: distance update packed as float2 (v_pk_*_f32), bit-identical
// per-component arithmetic in the identical order.
// ---------------------------------------------------------------------------
#define DPP_ROR_I(x, N) __builtin_amdgcn_update_dpp(0, (int)(x), 0x120 + (N), 0xf, 0xf, false)

__global__ __launch_bounds__(256) void fps_kernel(const float* __restrict__ xyz,
                                                  float* __restrict__ out_xyz) {
    __shared__ float4 pts4[NPTS];
    __shared__ float hx[NS], hy[NS], hz[NS];
    __shared__ unsigned wk[2][4][2];  // [buf][wave][kh,kl]

    const int b = blockIdx.x;
    const int t = threadIdx.x;
    const int wv = t >> 6;
    const int lane = t & 63;

    const float* xb = xyz + (size_t)b * NPTS * 3;
    for (int i = t; i < NPTS; i += 256) {
        pts4[i] = make_float4(xb[3 * i], xb[3 * i + 1], xb[3 * i + 2], 0.0f);
    }
    __syncthreads();

    // packed point-pair registers: PX[k] = (x of pt 2k, x of pt 2k+1), etc.
    v2f PX[8], PY[8], PZ[8];
    float dm[16];
#pragma unroll
    for (int k = 0; k < 8; ++k) {
        const float4 p0 = pts4[t + (2 * k) * 256];
        const float4 p1 = pts4[t + (2 * k + 1) * 256];
        PX[k].x = p0.x; PX[k].y = p1.x;
        PY[k].x = p0.y; PY[k].y = p1.y;
        PZ[k].x = p0.z; PZ[k].y = p1.z;
        dm[2 * k] = 1e10f; dm[2 * k + 1] = 1e10f;
    }

    const float4 c0 = pts4[0];
    float cx = c0.x, cy = c0.y, cz = c0.z;

    for (int s = 0; s < NS; ++s) {
        if (t == 0) { hx[s] = cx; hy[s] = cy; hz[s] = cz; }

        // packed min-dist update: per component identical op sequence to the
        // verified scalar form: d = (dx*dx + dy*dy) + dz*dz, then min.
        const v2f cX = { cx, cx };
        const v2f cY = { cy, cy };
        const v2f cZ = { cz, cz };
#pragma unroll
        for (int k = 0; k < 8; ++k) {
            const v2f dX = PX[k] - cX;
            const v2f dY = PY[k] - cY;
            const v2f dZ = PZ[k] - cZ;
            const v2f t1 = dX * dX;
            const v2f t2 = dY * dY;
            const v2f t3 = dZ * dZ;
            const v2f ss = (t1 + t2) + t3;
            dm[2 * k] = fminf(dm[2 * k], ss.x);
            dm[2 * k + 1] = fminf(dm[2 * k + 1], ss.y);
        }

        // lane max via depth-4 fmax tree
        float a8[8], a4[4], a2[2];
#pragma unroll
        for (int j = 0; j < 8; ++j) a8[j] = fmaxf(dm[2 * j], dm[2 * j + 1]);
#pragma unroll
        for (int j = 0; j < 4; ++j) a4[j] = fmaxf(a8[2 * j], a8[2 * j + 1]);
        a2[0] = fmaxf(a4[0], a4[1]);
        a2[1] = fmaxf(a4[2], a4[3]);
        const float mv = fmaxf(a2[0], a2[1]);

        // lane arg (lowest global idx among ties) via depth-4 min-u32 tree
        unsigned u16a[16], u8[8], u4[4], u2[2];
#pragma unroll
        for (int j = 0; j < 16; ++j)
            u16a[j] = (dm[j] == mv) ? (unsigned)(t + j * 256) : 0xFFFFFFFFu;
#pragma unroll
        for (int j = 0; j < 8; ++j) u8[j] = u16a[2 * j] < u16a[2 * j + 1] ? u16a[2 * j] : u16a[2 * j + 1];
#pragma unroll
        for (int j = 0; j < 4; ++j) u4[j] = u8[2 * j] < u8[2 * j + 1] ? u8[2 * j] : u8[2 * j + 1];
        u2[0] = u4[0] < u4[1] ? u4[0] : u4[1];
        u2[1] = u4[2] < u4[3] ? u4[2] : u4[3];
        const unsigned best = u2[0] < u2[1] ? u2[0] : u2[1];

        // wave max: 4x DPP row_ror f32-max (row all-reduce), readlane across rows
        float r = mv;
        { const float o = __int_as_float(DPP_ROR_I(__float_as_int(r), 1)); r = fmaxf(r, o); }
        { const float o = __int_as_float(DPP_ROR_I(__float_as_int(r), 2)); r = fmaxf(r, o); }
        { const float o = __int_as_float(DPP_ROR_I(__float_as_int(r), 4)); r = fmaxf(r, o); }
        { const float o = __int_as_float(DPP_ROR_I(__float_as_int(r), 8)); r = fmaxf(r, o); }
        const float q0 = __int_as_float(__builtin_amdgcn_readlane(__float_as_int(r), 0));
        const float q1 = __int_as_float(__builtin_amdgcn_readlane(__float_as_int(r), 16));
        const float q2 = __int_as_float(__builtin_amdgcn_readlane(__float_as_int(r), 32));
        const float q3 = __int_as_float(__builtin_amdgcn_readlane(__float_as_int(r), 48));
        const float wm = fmaxf(fmaxf(q0, q1), fmaxf(q2, q3));

        // wave arg: candidates where lane max == wave max, min-u32 all-reduce
        unsigned c = (mv == wm) ? best : 0xFFFFFFFFu;
        { const unsigned o = (unsigned)DPP_ROR_I(c, 1); c = o < c ? o : c; }
        { const unsigned o = (unsigned)DPP_ROR_I(c, 2); c = o < c ? o : c; }
        { const unsigned o = (unsigned)DPP_ROR_I(c, 4); c = o < c ? o : c; }
        { const unsigned o = (unsigned)DPP_ROR_I(c, 8); c = o < c ? o : c; }
        const unsigned g0 = (unsigned)__builtin_amdgcn_readlane((int)c, 0);
        const unsigned g1 = (unsigned)__builtin_amdgcn_readlane((int)c, 16);
        const unsigned g2 = (unsigned)__builtin_amdgcn_readlane((int)c, 32);
        const unsigned g3 = (unsigned)__builtin_amdgcn_readlane((int)c, 48);
        const unsigned ga = g0 < g1 ? g0 : g1;
        const unsigned gb = g2 < g3 ? g2 : g3;
        const unsigned wgi = ga < gb ? ga : gb;

        // cross-wave merge via double-buffered LDS keys (one barrier/iter)
        if (lane == 0) { wk[s & 1][wv][0] = __float_as_uint(wm); wk[s & 1][wv][1] = ~wgi; }
        __syncthreads();
        const unsigned long long k0 = ((unsigned long long)wk[s & 1][0][0] << 32) | wk[s & 1][0][1];
        const unsigned long long k1 = ((unsigned long long)wk[s & 1][1][0] << 32) | wk[s & 1][1][1];
        const unsigned long long k2 = ((unsigned long long)wk[s & 1][2][0] << 32) | wk[s & 1][2][1];
        const unsigned long long k3 = ((unsigned long long)wk[s & 1][3][0] << 32) | wk[s & 1][3][1];
        const unsigned long long ka = k0 > k1 ? k0 : k1;
        const unsigned long long kb = k2 > k3 ? k2 : k3;
        const unsigned long long kw = ka > kb ? ka : kb;

        const int wi = (int)(~(unsigned)kw);
        const float4 cc = pts4[wi];
        cx = cc.x; cy = cc.y; cz = cc.z;
    }

    // flush centroid history to global, coalesced
    __syncthreads();
    float* ob = out_xyz + (size_t)b * NS * 3;
#pragma unroll
    for (int r2 = 0; r2 < 12; ++r2) {
        const int f = t + r2 * 256;
        const int i = f / 3;
        const int cmp = f - 3 * i;
        const float v = (cmp == 0) ? hx[i] : ((cmp == 1) ? hy[i] : hz[i]);
        ob[f] = v;
    }
}

// ---------------------------------------------------------------------------
// KNN: one wave per query. fp32 expanded-form distances replicating the
// reference's rounding: dot as an FMA chain, d = (qsq - 2*dot) + psq,
// qsq/psq sequential no-FMA.  [R4-verified exact]
// Per-lane sorted top-4 + lazy refill; 32 rounds of wave argmin.
// ---------------------------------------------------------------------------
#define KNN_INF 3.0e38f

__global__ __launch_bounds__(1024) void knn_kernel(const float* __restrict__ xyz,
                                                   const float* __restrict__ newxyz,
                                                   unsigned short* __restrict__ knn) {
    __shared__ float4 pts[NPTS];

    const int b = blockIdx.x >> 6;
    const int t = threadIdx.x;
    const float* xb = xyz + (size_t)b * NPTS * 3;
    for (int i = t; i < NPTS; i += 1024) {
        const float x = xb[3 * i], y = xb[3 * i + 1], z = xb[3 * i + 2];
        const float ps = __fadd_rn(__fadd_rn(__fmul_rn(x, x), __fmul_rn(y, y)), __fmul_rn(z, z));
        pts[i] = make_float4(x, y, z, ps);
    }
    __syncthreads();

    const int lane = t & 63;
    const int wv = t >> 6;
    const int s = ((blockIdx.x & 63) << 4) + wv;

    const float* q = newxyz + ((size_t)b * NS + s) * 3;
    const float qx = q[0], qy = q[1], qz = q[2];
    const float qs = __fadd_rn(__fadd_rn(__fmul_rn(qx, qx), __fmul_rn(qy, qy)), __fmul_rn(qz, qz));

    float v0 = KNN_INF, v1 = KNN_INF, v2 = KNN_INF, v3 = KNN_INF;
    int i0 = 0, i1 = 0, i2 = 0, i3 = 0;
    unsigned long long rem = 0ull;

#pragma unroll 4
    for (int j = 0; j < 64; ++j) {
        const float4 p = pts[j * 64 + lane];
        const float dot = __fmaf_rn(qz, p.z, __fmaf_rn(qy, p.y, __fmul_rn(qx, p.x)));
        const float d = __fadd_rn(__fsub_rn(qs, __fadd_rn(dot, dot)), p.w);
        const int gi = j * 64 + lane;
        const bool c0 = d < v0, c1 = d < v1, c2 = d < v2, c3 = d < v3;
        v3 = c3 ? (c2 ? v2 : d) : v3;  i3 = c3 ? (c2 ? i2 : gi) : i3;
        v2 = c2 ? (c1 ? v1 : d) : v2;  i2 = c2 ? (c1 ? i1 : gi) : i2;
        v1 = c1 ? (c0 ? v0 : d) : v1;  i1 = c1 ? (c0 ? i0 : gi) : i1;
        v0 = c0 ? d : v0;              i0 = c0 ? gi : i0;
    }

    int kidx = 0;
#pragma unroll 1
    for (int r = 0; r < NK; ++r) {
        float bv = v0;
        int bi = i0;
#pragma unroll
        for (int m = 1; m < 64; m <<= 1) {
            const float ov = __shfl_xor(bv, m);
            const int   oi = __shfl_xor(bi, m);
            if (ov < bv || (ov == bv && oi < bi)) { bv = ov; bi = oi; }
        }
        if (lane == r) kidx = bi;
        if ((bi & 63) == lane) {
            v0 = v1; i0 = i1;
            v1 = v2; i1 = i2;
            v2 = v3; i2 = i3;
            v3 = KNN_INF;
            rem |= 1ull << (bi >> 6);
            if (v0 >= 1e37f) {
                v0 = v1 = v2 = v3 = KNN_INF;
#pragma unroll 1
                for (int j = 0; j < 64; ++j) {
                    if (!((rem >> j) & 1ull)) {
                        const float4 p = pts[j * 64 + lane];
                        const float dot = __fmaf_rn(qz, p.z, __fmaf_rn(qy, p.y, __fmul_rn(qx, p.x)));
                        const float d = __fadd_rn(__fsub_rn(qs, __fadd_rn(dot, dot)), p.w);
                        const int gi = j * 64 + lane;
                        const bool c0 = d < v0, c1 = d < v1, c2 = d < v2, c3 = d < v3;
                        v3 = c3 ? (c2 ? v2 : d) : v3;  i3 = c3 ? (c2 ? i2 : gi) : i3;
                        v2 = c2 ? (c1 ? v1 : d) : v2;  i2 = c2 ? (c1 ? i1 : gi) : i2;
                        v1 = c1 ? (c0 ? v0 : d) : v1;  i1 = c1 ? (c0 ? i0 : gi) : i1;
                        v0 = c0 ? d : v0;              i0 = c0 ? gi : i0;
                    }
                }
            }
        }
    }

    if (lane < NK) knn[(((size_t)b * NS + s) << 5) + lane] = (unsigned short)kidx;
}

// ---------------------------------------------------------------------------
// Gather + 3-layer 1x1-conv MLP + max-pool over K.
// One lane per (group, neighbor) row; 2 groups per wave; 8 groups per block.
// ---------------------------------------------------------------------------
__global__ __launch_bounds__(256) void mlp_kernel(const float* __restrict__ xyz,
                                                  const float* __restrict__ points,
                                                  const float* __restrict__ newxyz,
                                                  const unsigned short* __restrict__ knn,
                                                  const float* __restrict__ w0, const float* __restrict__ b0,
                                                  const float* __restrict__ w1, const float* __restrict__ b1,
                                                  const float* __restrict__ w2, const float* __restrict__ b2,
                                                  float* __restrict__ out) {
    __shared__ float act[67][256];

    const int t = threadIdx.x;
    const int lane = t & 63;
    const int g = blockIdx.x * 8 + ((t >> 6) << 1) + ((lane >> 5) & 1);
    const int b = g >> 10;
    const int k = lane & 31;

    const int idx = knn[((size_t)g << 5) + k];
    const float* nq = newxyz + (size_t)g * 3;
    const float* pp = xyz + ((size_t)b * NPTS + idx) * 3;
    act[0][t] = pp[0] - nq[0];
    act[1][t] = pp[1] - nq[1];
    act[2][t] = pp[2] - nq[2];
    const float4* pr = (const float4*)(points + (((size_t)b * NPTS + idx) << 6));
#pragma unroll
    for (int j = 0; j < 16; ++j) {
        const float4 v = pr[j];
        act[3 + 4 * j][t] = v.x;
        act[4 + 4 * j][t] = v.y;
        act[5 + 4 * j][t] = v.z;
        act[6 + 4 * j][t] = v.w;
    }

    float h[128];

    // layer 1: 67 -> 64
#pragma unroll
    for (int f = 0; f < 64; ++f) h[f] = b0[f];
#pragma unroll 1
    for (int i = 0; i < 67; ++i) {
        const float xi = act[i][t];
        const float* wr = w0 + (i << 6);
#pragma unroll
        for (int f = 0; f < 64; ++f) h[f] = fmaf(xi, wr[f], h[f]);
    }
#pragma unroll
    for (int f = 0; f < 64; ++f) act[f][t] = fmaxf(h[f], 0.0f);

    // layer 2: 64 -> 64
#pragma unroll
    for (int f = 0; f < 64; ++f) h[f] = b1[f];
#pragma unroll 1
    for (int i = 0; i < 64; ++i) {
        const float xi = act[i][t];
        const float* wr = w1 + (i << 6);
#pragma unroll
        for (int f = 0; f < 64; ++f) h[f] = fmaf(xi, wr[f], h[f]);
    }
#pragma unroll
    for (int f = 0; f < 64; ++f) act[f][t] = fmaxf(h[f], 0.0f);

    // layer 3: 64 -> 128
#pragma unroll
    for (int f = 0; f < 128; ++f) h[f] = b2[f];
#pragma unroll 1
    for (int i = 0; i < 64; ++i) {
        const float xi = act[i][t];
        const float* wr = w2 + (i << 7);
#pragma unroll
        for (int f = 0; f < 128; ++f) h[f] = fmaf(xi, wr[f], h[f]);
    }
#pragma unroll
    for (int f = 0; f < 128; ++f) h[f] = fmaxf(h[f], 0.0f);

    // butterfly reduce-scatter max over the 32 lanes of each half-wave.
    float t64[64];
#pragma unroll
    for (int c = 0; c < 64; ++c) {
        const bool hi = (lane & 16);
        const float kept = hi ? h[c + 64] : h[c];
        const float snt  = hi ? h[c] : h[c + 64];
        t64[c] = fmaxf(kept, __shfl_xor(snt, 16));
    }
    float t32a[32];
#pragma unroll
    for (int c = 0; c < 32; ++c) {
        const bool hi = (lane & 8);
        const float kept = hi ? t64[c + 32] : t64[c];
        const float snt  = hi ? t64[c] : t64[c + 32];
        t32a[c] = fmaxf(kept, __shfl_xor(snt, 8));
    }
    float t16a[16];
#pragma unroll
    for (int c = 0; c < 16; ++c) {
        const bool hi = (lane & 4);
        const float kept = hi ? t32a[c + 16] : t32a[c];
        const float snt  = hi ? t32a[c] : t32a[c + 16];
        t16a[c] = fmaxf(kept, __shfl_xor(snt, 4));
    }
    float t8a[8];
#pragma unroll
    for (int c = 0; c < 8; ++c) {
        const bool hi = (lane & 2);
        const float kept = hi ? t16a[c + 8] : t16a[c];
        const float snt  = hi ? t16a[c] : t16a[c + 8];
        t8a[c] = fmaxf(kept, __shfl_xor(snt, 2));
    }
    float t4a[4];
#pragma unroll
    for (int c = 0; c < 4; ++c) {
        const bool hi = (lane & 1);
        const float kept = hi ? t8a[c + 4] : t8a[c];
        const float snt  = hi ? t8a[c] : t8a[c + 4];
        t4a[c] = fmaxf(kept, __shfl_xor(snt, 1));
    }

    float* op = out + (size_t)g * 128 + ((lane & 31) << 2);
    *(float4*)op = make_float4(t4a[0], t4a[1], t4a[2], t4a[3]);
}

extern "C" void kernel_launch(void* const* d_in, const int* in_sizes, int n_in,
                              void* d_out, int out_size, void* d_ws, size_t ws_size,
                              hipStream_t stream) {
    const float* xyz    = (const float*)d_in[0];
    const float* points = (const float*)d_in[1];
    const float* w0 = (const float*)d_in[2];
    const float* b0 = (const float*)d_in[3];
    const float* w1 = (const float*)d_in[4];
    const float* b1 = (const float*)d_in[5];
    const float* w2 = (const float*)d_in[6];
    const float* b2 = (const float*)d_in[7];

    float* out = (float*)d_out;
    float* newxyz = out;                          // (B, S, 3)
    float* newpts = out + (size_t)NB * NS * 3;    // (B, S, 128)
    unsigned short* knn = (unsigned short*)d_ws;  // (B, S, K) u16, 1 MB

    fps_kernel<<<NB, 256, 0, stream>>>(xyz, newxyz);
    knn_kernel<<<NB * (NS / 16), 1024, 0, stream>>>(xyz, newxyz, knn);
    mlp_kernel<<<(NB * NS) / 8, 256, 0, stream>>>(xyz, points, newxyz, knn,
                                                  w0, b0, w1, b1, w2, b2, newpts);
}

// Round 10
// 943.380 us; speedup vs baseline: 1.2352x; 1.0184x over previous
//
#include <hip/hip_runtime.h>

#define NB 16
#define NPTS 4096
#define NC 64
#define NS 1024
#define NK 32

typedef float v2f __attribute__((ext_vector_type(2)));

#define DPP_ROR_I(x, N) __builtin_amdgcn_update_dpp(0, (int)(x), 0x120 + (N), 0xf, 0xf, false)

static __device__ __forceinline__ float max3f(float a, float b, float c) {
    return fmaxf(fmaxf(a, b), c);   // fuses to v_max3_f32
}
static __device__ __forceinline__ unsigned min3u(unsigned a, unsigned b, unsigned c) {
    const unsigned m = a < b ? a : b;
    return m < c ? m : c;           // fuses to v_min3_u32
}

// ---------------------------------------------------------------------------
// FPS: one block per batch, 256 threads (4 waves), 16 points/lane (pk f32
// pairs). Structure = R9 verified optimum. R10: ternary max3/min3 lane trees
// (identical selection semantics, fewer instructions).
// ---------------------------------------------------------------------------
__global__ __launch_bounds__(256) void fps_kernel(const float* __restrict__ xyz,
                                                  float* __restrict__ out_xyz) {
    __shared__ float4 pts4[NPTS];
    __shared__ float hx[NS], hy[NS], hz[NS];
    __shared__ unsigned wk[2][4][2];  // [buf][wave][kh,kl]

    const int b = blockIdx.x;
    const int t = threadIdx.x;
    const int wv = t >> 6;
    const int lane = t & 63;

    const float* xb = xyz + (size_t)b * NPTS * 3;
    for (int i = t; i < NPTS; i += 256) {
        pts4[i] = make_float4(xb[3 * i], xb[3 * i + 1], xb[3 * i + 2], 0.0f);
    }
    __syncthreads();

    // packed point-pair registers: PX[k] = (x of pt 2k, x of pt 2k+1), etc.
    v2f PX[8], PY[8], PZ[8];
    float dm[16];
#pragma unroll
    for (int k = 0; k < 8; ++k) {
        const float4 p0 = pts4[t + (2 * k) * 256];
        const float4 p1 = pts4[t + (2 * k + 1) * 256];
        PX[k].x = p0.x; PX[k].y = p1.x;
        PY[k].x = p0.y; PY[k].y = p1.y;
        PZ[k].x = p0.z; PZ[k].y = p1.z;
        dm[2 * k] = 1e10f; dm[2 * k + 1] = 1e10f;
    }

    const float4 c0 = pts4[0];
    float cx = c0.x, cy = c0.y, cz = c0.z;

    for (int s = 0; s < NS; ++s) {
        if (t == 0) { hx[s] = cx; hy[s] = cy; hz[s] = cz; }

        // packed min-dist update (bit-identical per-component arithmetic)
        const v2f cX = { cx, cx };
        const v2f cY = { cy, cy };
        const v2f cZ = { cz, cz };
#pragma unroll
        for (int k = 0; k < 8; ++k) {
            const v2f dX = PX[k] - cX;
            const v2f dY = PY[k] - cY;
            const v2f dZ = PZ[k] - cZ;
            const v2f t1 = dX * dX;
            const v2f t2 = dY * dY;
            const v2f t3 = dZ * dZ;
            const v2f ss = (t1 + t2) + t3;
            dm[2 * k] = fminf(dm[2 * k], ss.x);
            dm[2 * k + 1] = fminf(dm[2 * k + 1], ss.y);
        }

        // lane max via ternary max3 tree (depth 3)
        const float ta = max3f(dm[0], dm[1], dm[2]);
        const float tb = max3f(dm[3], dm[4], dm[5]);
        const float tc = max3f(dm[6], dm[7], dm[8]);
        const float td = max3f(dm[9], dm[10], dm[11]);
        const float te = max3f(dm[12], dm[13], dm[14]);
        const float mv = fmaxf(max3f(ta, tb, tc), max3f(td, te, dm[15]));

        // lane arg (lowest global idx among ties) via min3 tree
        unsigned u[16];
#pragma unroll
        for (int j = 0; j < 16; ++j)
            u[j] = (dm[j] == mv) ? (unsigned)(t + j * 256) : 0xFFFFFFFFu;
        const unsigned ua = min3u(u[0], u[1], u[2]);
        const unsigned ub = min3u(u[3], u[4], u[5]);
        const unsigned uc = min3u(u[6], u[7], u[8]);
        const unsigned ud = min3u(u[9], u[10], u[11]);
        const unsigned ue = min3u(u[12], u[13], u[14]);
        const unsigned uf = min3u(ua, ub, uc);
        const unsigned ug = min3u(ud, ue, u[15]);
        const unsigned best = uf < ug ? uf : ug;

        // wave max: 4x DPP row_ror f32-max (row all-reduce), readlane across rows
        float r = mv;
        { const float o = __int_as_float(DPP_ROR_I(__float_as_int(r), 1)); r = fmaxf(r, o); }
        { const float o = __int_as_float(DPP_ROR_I(__float_as_int(r), 2)); r = fmaxf(r, o); }
        { const float o = __int_as_float(DPP_ROR_I(__float_as_int(r), 4)); r = fmaxf(r, o); }
        { const float o = __int_as_float(DPP_ROR_I(__float_as_int(r), 8)); r = fmaxf(r, o); }
        const float q0 = __int_as_float(__builtin_amdgcn_readlane(__float_as_int(r), 0));
        const float q1 = __int_as_float(__builtin_amdgcn_readlane(__float_as_int(r), 16));
        const float q2 = __int_as_float(__builtin_amdgcn_readlane(__float_as_int(r), 32));
        const float q3 = __int_as_float(__builtin_amdgcn_readlane(__float_as_int(r), 48));
        const float wm = fmaxf(fmaxf(q0, q1), fmaxf(q2, q3));

        // wave arg: candidates where lane max == wave max, min-u32 all-reduce
        unsigned c = (mv == wm) ? best : 0xFFFFFFFFu;
        { const unsigned o = (unsigned)DPP_ROR_I(c, 1); c = o < c ? o : c; }
        { const unsigned o = (unsigned)DPP_ROR_I(c, 2); c = o < c ? o : c; }
        { const unsigned o = (unsigned)DPP_ROR_I(c, 4); c = o < c ? o : c; }
        { const unsigned o = (unsigned)DPP_ROR_I(c, 8); c = o < c ? o : c; }
        const unsigned g0 = (unsigned)__builtin_amdgcn_readlane((int)c, 0);
        const unsigned g1 = (unsigned)__builtin_amdgcn_readlane((int)c, 16);
        const unsigned g2 = (unsigned)__builtin_amdgcn_readlane((int)c, 32);
        const unsigned g3 = (unsigned)__builtin_amdgcn_readlane((int)c, 48);
        const unsigned ga = g0 < g1 ? g0 : g1;
        const unsigned gb = g2 < g3 ? g2 : g3;
        const unsigned wgi = ga < gb ? ga : gb;

        // cross-wave merge via double-buffered LDS keys (one barrier/iter)
        if (lane == 0) { wk[s & 1][wv][0] = __float_as_uint(wm); wk[s & 1][wv][1] = ~wgi; }
        __syncthreads();
        const unsigned long long k0 = ((unsigned long long)wk[s & 1][0][0] << 32) | wk[s & 1][0][1];
        const unsigned long long k1 = ((unsigned long long)wk[s & 1][1][0] << 32) | wk[s & 1][1][1];
        const unsigned long long k2 = ((unsigned long long)wk[s & 1][2][0] << 32) | wk[s & 1][2][1];
        const unsigned long long k3 = ((unsigned long long)wk[s & 1][3][0] << 32) | wk[s & 1][3][1];
        const unsigned long long ka = k0 > k1 ? k0 : k1;
        const unsigned long long kb = k2 > k3 ? k2 : k3;
        const unsigned long long kw = ka > kb ? ka : kb;

        const int wi = (int)(~(unsigned)kw);
        const float4 cc = pts4[wi];
        cx = cc.x; cy = cc.y; cz = cc.z;
    }

    // flush centroid history to global, coalesced
    __syncthreads();
    float* ob = out_xyz + (size_t)b * NS * 3;
#pragma unroll
    for (int r2 = 0; r2 < 12; ++r2) {
        const int f = t + r2 * 256;
        const int i = f / 3;
        const int cmp = f - 3 * i;
        const float v = (cmp == 0) ? hx[i] : ((cmp == 1) ? hy[i] : hz[i]);
        ob[f] = v;
    }
}

// ---------------------------------------------------------------------------
// KNN: one wave per query. fp32 expanded-form distances replicating the
// reference's rounding (FMA-chain dot).  [R4-verified exact]
// Per-lane sorted top-4 + lazy refill. R10: per-round wave argmin via
// two-pass DPP row-reduce (f32-min then idx min-u32 among value matches) —
// provably identical selection to the lexicographic shfl chain, but on the
// VALU/DPP path instead of 6 dependent ds_bpermutes.
// ---------------------------------------------------------------------------
#define KNN_INF 3.0e38f

__global__ __launch_bounds__(1024) void knn_kernel(const float* __restrict__ xyz,
                                                   const float* __restrict__ newxyz,
                                                   unsigned short* __restrict__ knn) {
    __shared__ float4 pts[NPTS];

    const int b = blockIdx.x >> 6;
    const int t = threadIdx.x;
    const float* xb = xyz + (size_t)b * NPTS * 3;
    for (int i = t; i < NPTS; i += 1024) {
        const float x = xb[3 * i], y = xb[3 * i + 1], z = xb[3 * i + 2];
        const float ps = __fadd_rn(__fadd_rn(__fmul_rn(x, x), __fmul_rn(y, y)), __fmul_rn(z, z));
        pts[i] = make_float4(x, y, z, ps);
    }
    __syncthreads();

    const int lane = t & 63;
    const int wv = t >> 6;
    const int s = ((blockIdx.x & 63) << 4) + wv;

    const float* q = newxyz + ((size_t)b * NS + s) * 3;
    const float qx = q[0], qy = q[1], qz = q[2];
    const float qs = __fadd_rn(__fadd_rn(__fmul_rn(qx, qx), __fmul_rn(qy, qy)), __fmul_rn(qz, qz));

    float v0 = KNN_INF, v1 = KNN_INF, v2 = KNN_INF, v3 = KNN_INF;
    int i0 = 0, i1 = 0, i2 = 0, i3 = 0;
    unsigned long long rem = 0ull;

#pragma unroll 4
    for (int j = 0; j < 64; ++j) {
        const float4 p = pts[j * 64 + lane];
        const float dot = __fmaf_rn(qz, p.z, __fmaf_rn(qy, p.y, __fmul_rn(qx, p.x)));
        const float d = __fadd_rn(__fsub_rn(qs, __fadd_rn(dot, dot)), p.w);
        const int gi = j * 64 + lane;
        const bool c0 = d < v0, c1 = d < v1, c2 = d < v2, c3 = d < v3;
        v3 = c3 ? (c2 ? v2 : d) : v3;  i3 = c3 ? (c2 ? i2 : gi) : i3;
        v2 = c2 ? (c1 ? v1 : d) : v2;  i2 = c2 ? (c1 ? i1 : gi) : i2;
        v1 = c1 ? (c0 ? v0 : d) : v1;  i1 = c1 ? (c0 ? i0 : gi) : i1;
        v0 = c0 ? d : v0;              i0 = c0 ? gi : i0;
    }

    int kidx = 0;
#pragma unroll 1
    for (int r = 0; r < NK; ++r) {
        // two-pass wave argmin: value min all-reduce, then idx min among ties
        float rv = v0;
        { const float o = __int_as_float(DPP_ROR_I(__float_as_int(rv), 1)); rv = fminf(rv, o); }
        { const float o = __int_as_float(DPP_ROR_I(__float_as_int(rv), 2)); rv = fminf(rv, o); }
        { const float o = __int_as_float(DPP_ROR_I(__float_as_int(rv), 4)); rv = fminf(rv, o); }
        { const float o = __int_as_float(DPP_ROR_I(__float_as_int(rv), 8)); rv = fminf(rv, o); }
        const float q0v = __int_as_float(__builtin_amdgcn_readlane(__float_as_int(rv), 0));
        const float q1v = __int_as_float(__builtin_amdgcn_readlane(__float_as_int(rv), 16));
        const float q2v = __int_as_float(__builtin_amdgcn_readlane(__float_as_int(rv), 32));
        const float q3v = __int_as_float(__builtin_amdgcn_readlane(__float_as_int(rv), 48));
        const float wm = fminf(fminf(q0v, q1v), fminf(q2v, q3v));

        unsigned cand = (v0 == wm) ? (unsigned)i0 : 0x7FFFFFFFu;
        { const unsigned o = (unsigned)DPP_ROR_I(cand, 1); cand = o < cand ? o : cand; }
        { const unsigned o = (unsigned)DPP_ROR_I(cand, 2); cand = o < cand ? o : cand; }
        { const unsigned o = (unsigned)DPP_ROR_I(cand, 4); cand = o < cand ? o : cand; }
        { const unsigned o = (unsigned)DPP_ROR_I(cand, 8); cand = o < cand ? o : cand; }
        const unsigned c0r = (unsigned)__builtin_amdgcn_readlane((int)cand, 0);
        const unsigned c1r = (unsigned)__builtin_amdgcn_readlane((int)cand, 16);
        const unsigned c2r = (unsigned)__builtin_amdgcn_readlane((int)cand, 32);
        const unsigned c3r = (unsigned)__builtin_amdgcn_readlane((int)cand, 48);
        const unsigned ca = c0r < c1r ? c0r : c1r;
        const unsigned cb = c2r < c3r ? c2r : c3r;
        const int bi = (int)(ca < cb ? ca : cb);

        if (lane == r) kidx = bi;
        if ((bi & 63) == lane) {
            v0 = v1; i0 = i1;
            v1 = v2; i1 = i2;
            v2 = v3; i2 = i3;
            v3 = KNN_INF;
            rem |= 1ull << (bi >> 6);
            if (v0 >= 1e37f) {
                v0 = v1 = v2 = v3 = KNN_INF;
#pragma unroll 1
                for (int j = 0; j < 64; ++j) {
                    if (!((rem >> j) & 1ull)) {
                        const float4 p = pts[j * 64 + lane];
                        const float dot = __fmaf_rn(qz, p.z, __fmaf_rn(qy, p.y, __fmul_rn(qx, p.x)));
                        const float d = __fadd_rn(__fsub_rn(qs, __fadd_rn(dot, dot)), p.w);
                        const int gi = j * 64 + lane;
                        const bool c0 = d < v0, c1 = d < v1, c2 = d < v2, c3 = d < v3;
                        v3 = c3 ? (c2 ? v2 : d) : v3;  i3 = c3 ? (c2 ? i2 : gi) : i3;
                        v2 = c2 ? (c1 ? v1 : d) : v2;  i2 = c2 ? (c1 ? i1 : gi) : i2;
                        v1 = c1 ? (c0 ? v0 : d) : v1;  i1 = c1 ? (c0 ? i0 : gi) : i1;
                        v0 = c0 ? d : v0;              i0 = c0 ? gi : i0;
                    }
                }
            }
        }
    }

    if (lane < NK) knn[(((size_t)b * NS + s) << 5) + lane] = (unsigned short)kidx;
}

// ---------------------------------------------------------------------------
// Gather + 3-layer 1x1-conv MLP + max-pool over K. (unchanged, fp32 roofline)
// ---------------------------------------------------------------------------
__global__ __launch_bounds__(256) void mlp_kernel(const float* __restrict__ xyz,
                                                  const float* __restrict__ points,
                                                  const float* __restrict__ newxyz,
                                                  const unsigned short* __restrict__ knn,
                                                  const float* __restrict__ w0, const float* __restrict__ b0,
                                                  const float* __restrict__ w1, const float* __restrict__ b1,
                                                  const float* __restrict__ w2, const float* __restrict__ b2,
                                                  float* __restrict__ out) {
    __shared__ float act[67][256];

    const int t = threadIdx.x;
    const int lane = t & 63;
    const int g = blockIdx.x * 8 + ((t >> 6) << 1) + ((lane >> 5) & 1);
    const int b = g >> 10;
    const int k = lane & 31;

    const int idx = knn[((size_t)g << 5) + k];
    const float* nq = newxyz + (size_t)g * 3;
    const float* pp = xyz + ((size_t)b * NPTS + idx) * 3;
    act[0][t] = pp[0] - nq[0];
    act[1][t] = pp[1] - nq[1];
    act[2][t] = pp[2] - nq[2];
    const float4* pr = (const float4*)(points + (((size_t)b * NPTS + idx) << 6));
#pragma unroll
    for (int j = 0; j < 16; ++j) {
        const float4 v = pr[j];
        act[3 + 4 * j][t] = v.x;
        act[4 + 4 * j][t] = v.y;
        act[5 + 4 * j][t] = v.z;
        act[6 + 4 * j][t] = v.w;
    }

    float h[128];

    // layer 1: 67 -> 64
#pragma unroll
    for (int f = 0; f < 64; ++f) h[f] = b0[f];
#pragma unroll 1
    for (int i = 0; i < 67; ++i) {
        const float xi = act[i][t];
        const float* wr = w0 + (i << 6);
#pragma unroll
        for (int f = 0; f < 64; ++f) h[f] = fmaf(xi, wr[f], h[f]);
    }
#pragma unroll
    for (int f = 0; f < 64; ++f) act[f][t] = fmaxf(h[f], 0.0f);

    // layer 2: 64 -> 64
#pragma unroll
    for (int f = 0; f < 64; ++f) h[f] = b1[f];
#pragma unroll 1
    for (int i = 0; i < 64; ++i) {
        const float xi = act[i][t];
        const float* wr = w1 + (i << 6);
#pragma unroll
        for (int f = 0; f < 64; ++f) h[f] = fmaf(xi, wr[f], h[f]);
    }
#pragma unroll
    for (int f = 0; f < 64; ++f) act[f][t] = fmaxf(h[f], 0.0f);

    // layer 3: 64 -> 128
#pragma unroll
    for (int f = 0; f < 128; ++f) h[f] = b2[f];
#pragma unroll 1
    for (int i = 0; i < 64; ++i) {
        const float xi = act[i][t];
        const float* wr = w2 + (i << 7);
#pragma unroll
        for (int f = 0; f < 128; ++f) h[f] = fmaf(xi, wr[f], h[f]);
    }
#pragma unroll
    for (int f = 0; f < 128; ++f) h[f] = fmaxf(h[f], 0.0f);

    // butterfly reduce-scatter max over the 32 lanes of each half-wave.
    float t64[64];
#pragma unroll
    for (int c = 0; c < 64; ++c) {
        const bool hi = (lane & 16);
        const float kept = hi ? h[c + 64] : h[c];
        const float snt  = hi ? h[c] : h[c + 64];
        t64[c] = fmaxf(kept, __shfl_xor(snt, 16));
    }
    float t32a[32];
#pragma unroll
    for (int c = 0; c < 32; ++c) {
        const bool hi = (lane & 8);
        const float kept = hi ? t64[c + 32] : t64[c];
        const float snt  = hi ? t64[c] : t64[c + 32];
        t32a[c] = fmaxf(kept, __shfl_xor(snt, 8));
    }
    float t16a[16];
#pragma unroll
    for (int c = 0; c < 16; ++c) {
        const bool hi = (lane & 4);
        const float kept = hi ? t32a[c + 16] : t32a[c];
        const float snt  = hi ? t32a[c] : t32a[c + 16];
        t16a[c] = fmaxf(kept, __shfl_xor(snt, 4));
    }
    float t8a[8];
#pragma unroll
    for (int c = 0; c < 8; ++c) {
        const bool hi = (lane & 2);
        const float kept = hi ? t16a[c + 8] : t16a[c];
        const float snt  = hi ? t16a[c] : t16a[c + 8];
        t8a[c] = fmaxf(kept, __shfl_xor(snt, 2));
    }
    float t4a[4];
#pragma unroll
    for (int c = 0; c < 4; ++c) {
        const bool hi = (lane & 1);
        const float kept = hi ? t8a[c + 4] : t8a[c];
        const float snt  = hi ? t8a[c] : t8a[c + 4];
        t4a[c] = fmaxf(kept, __shfl_xor(snt, 1));
    }

    float* op = out + (size_t)g * 128 + ((lane & 31) << 2);
    *(float4*)op = make_float4(t4a[0], t4a[1], t4a[2], t4a[3]);
}

extern "C" void kernel_launch(void* const* d_in, const int* in_sizes, int n_in,
                              void* d_out, int out_size, void* d_ws, size_t ws_size,
                              hipStream_t stream) {
    const float* xyz    = (const float*)d_in[0];
    const float* points = (const float*)d_in[1];
    const float* w0 = (const float*)d_in[2];
    const float* b0 = (const float*)d_in[3];
    const float* w1 = (const float*)d_in[4];
    const float* b1 = (const float*)d_in[5];
    const float* w2 = (const float*)d_in[6];
    const float* b2 = (const float*)d_in[7];

    float* out = (float*)d_out;
    float* newxyz = out;                          // (B, S, 3)
    float* newpts = out + (size_t)NB * NS * 3;    // (B, S, 128)
    unsigned short* knn = (unsigned short*)d_ws;  // (B, S, K) u16, 1 MB

    fps_kernel<<<NB, 256, 0, stream>>>(xyz, newxyz);
    knn_kernel<<<NB * (NS / 16), 1024, 0, stream>>>(xyz, newxyz, knn);
    mlp_kernel<<<(NB * NS) / 8, 256, 0, stream>>>(xyz, points, newxyz, knn,
                                                  w0, b0, w1, b1, w2, b2, newpts);
}

// Round 11
// 820.860 us; speedup vs baseline: 1.4196x; 1.1493x over previous
//
#include <hip/hip_runtime.h>

#define NB 16
#define NPTS 4096
#define NC 64
#define NS 1024
#define NK 32

typedef float v2f __attribute__((ext_vector_type(2)));
typedef short bf16x8 __attribute__((ext_vector_type(8)));
typedef float f32x4 __attribute__((ext_vector_type(4)));

#define DPP_ROR_I(x, N) __builtin_amdgcn_update_dpp(0, (int)(x), 0x120 + (N), 0xf, 0xf, false)
#define MFMA16(a, b, c) __builtin_amdgcn_mfma_f32_16x16x32_bf16((a), (b), (c), 0, 0, 0)

static __device__ __forceinline__ float max3f(float a, float b, float c) {
    return fmaxf(fmaxf(a, b), c);
}
static __device__ __forceinline__ unsigned min3u(unsigned a, unsigned b, unsigned c) {
    const unsigned m = a < b ? a : b;
    return m < c ? m : c;
}
static __device__ __forceinline__ unsigned short f2bf(float f) {
    const unsigned u = __float_as_uint(f);
    const unsigned r = 0x7FFFu + ((u >> 16) & 1u);
    return (unsigned short)((u + r) >> 16);
}
static __device__ __forceinline__ float bf2f(unsigned short h) {
    return __uint_as_float(((unsigned)h) << 16);
}
static __device__ __forceinline__ unsigned pkhi(float a, float b) {
    return (unsigned)f2bf(a) | ((unsigned)f2bf(b) << 16);
}
static __device__ __forceinline__ unsigned pklo(float a, float b) {
    const float la = a - bf2f(f2bf(a));
    const float lb = b - bf2f(f2bf(b));
    return (unsigned)f2bf(la) | ((unsigned)f2bf(lb) << 16);
}

// ---------------------------------------------------------------------------
// FPS: unchanged from R10 (verified 637 us, bit-exact selection).
// ---------------------------------------------------------------------------
__global__ __launch_bounds__(256) void fps_kernel(const float* __restrict__ xyz,
                                                  float* __restrict__ out_xyz) {
    __shared__ float4 pts4[NPTS];
    __shared__ float hx[NS], hy[NS], hz[NS];
    __shared__ unsigned wk[2][4][2];

    const int b = blockIdx.x;
    const int t = threadIdx.x;
    const int wv = t >> 6;
    const int lane = t & 63;

    const float* xb = xyz + (size_t)b * NPTS * 3;
    for (int i = t; i < NPTS; i += 256) {
        pts4[i] = make_float4(xb[3 * i], xb[3 * i + 1], xb[3 * i + 2], 0.0f);
    }
    __syncthreads();

    v2f PX[8], PY[8], PZ[8];
    float dm[16];
#pragma unroll
    for (int k = 0; k < 8; ++k) {
        const float4 p0 = pts4[t + (2 * k) * 256];
        const float4 p1 = pts4[t + (2 * k + 1) * 256];
        PX[k].x = p0.x; PX[k].y = p1.x;
        PY[k].x = p0.y; PY[k].y = p1.y;
        PZ[k].x = p0.z; PZ[k].y = p1.z;
        dm[2 * k] = 1e10f; dm[2 * k + 1] = 1e10f;
    }

    const float4 c0 = pts4[0];
    float cx = c0.x, cy = c0.y, cz = c0.z;

    for (int s = 0; s < NS; ++s) {
        if (t == 0) { hx[s] = cx; hy[s] = cy; hz[s] = cz; }

        const v2f cX = { cx, cx };
        const v2f cY = { cy, cy };
        const v2f cZ = { cz, cz };
#pragma unroll
        for (int k = 0; k < 8; ++k) {
            const v2f dX = PX[k] - cX;
            const v2f dY = PY[k] - cY;
            const v2f dZ = PZ[k] - cZ;
            const v2f t1 = dX * dX;
            const v2f t2 = dY * dY;
            const v2f t3 = dZ * dZ;
            const v2f ss = (t1 + t2) + t3;
            dm[2 * k] = fminf(dm[2 * k], ss.x);
            dm[2 * k + 1] = fminf(dm[2 * k + 1], ss.y);
        }

        const float ta = max3f(dm[0], dm[1], dm[2]);
        const float tb = max3f(dm[3], dm[4], dm[5]);
        const float tc = max3f(dm[6], dm[7], dm[8]);
        const float td = max3f(dm[9], dm[10], dm[11]);
        const float te = max3f(dm[12], dm[13], dm[14]);
        const float mv = fmaxf(max3f(ta, tb, tc), max3f(td, te, dm[15]));

        unsigned u[16];
#pragma unroll
        for (int j = 0; j < 16; ++j)
            u[j] = (dm[j] == mv) ? (unsigned)(t + j * 256) : 0xFFFFFFFFu;
        const unsigned ua = min3u(u[0], u[1], u[2]);
        const unsigned ub = min3u(u[3], u[4], u[5]);
        const unsigned uc = min3u(u[6], u[7], u[8]);
        const unsigned ud = min3u(u[9], u[10], u[11]);
        const unsigned ue = min3u(u[12], u[13], u[14]);
        const unsigned uf = min3u(ua, ub, uc);
        const unsigned ug = min3u(ud, ue, u[15]);
        const unsigned best = uf < ug ? uf : ug;

        float r = mv;
        { const float o = __int_as_float(DPP_ROR_I(__float_as_int(r), 1)); r = fmaxf(r, o); }
        { const float o = __int_as_float(DPP_ROR_I(__float_as_int(r), 2)); r = fmaxf(r, o); }
        { const float o = __int_as_float(DPP_ROR_I(__float_as_int(r), 4)); r = fmaxf(r, o); }
        { const float o = __int_as_float(DPP_ROR_I(__float_as_int(r), 8)); r = fmaxf(r, o); }
        const float q0 = __int_as_float(__builtin_amdgcn_readlane(__float_as_int(r), 0));
        const float q1 = __int_as_float(__builtin_amdgcn_readlane(__float_as_int(r), 16));
        const float q2 = __int_as_float(__builtin_amdgcn_readlane(__float_as_int(r), 32));
        const float q3 = __int_as_float(__builtin_amdgcn_readlane(__float_as_int(r), 48));
        const float wm = fmaxf(fmaxf(q0, q1), fmaxf(q2, q3));

        unsigned c = (mv == wm) ? best : 0xFFFFFFFFu;
        { const unsigned o = (unsigned)DPP_ROR_I(c, 1); c = o < c ? o : c; }
        { const unsigned o = (unsigned)DPP_ROR_I(c, 2); c = o < c ? o : c; }
        { const unsigned o = (unsigned)DPP_ROR_I(c, 4); c = o < c ? o : c; }
        { const unsigned o = (unsigned)DPP_ROR_I(c, 8); c = o < c ? o : c; }
        const unsigned g0 = (unsigned)__builtin_amdgcn_readlane((int)c, 0);
        const unsigned g1 = (unsigned)__builtin_amdgcn_readlane((int)c, 16);
        const unsigned g2 = (unsigned)__builtin_amdgcn_readlane((int)c, 32);
        const unsigned g3 = (unsigned)__builtin_amdgcn_readlane((int)c, 48);
        const unsigned ga = g0 < g1 ? g0 : g1;
        const unsigned gb = g2 < g3 ? g2 : g3;
        const unsigned wgi = ga < gb ? ga : gb;

        if (lane == 0) { wk[s & 1][wv][0] = __float_as_uint(wm); wk[s & 1][wv][1] = ~wgi; }
        __syncthreads();
        const unsigned long long k0 = ((unsigned long long)wk[s & 1][0][0] << 32) | wk[s & 1][0][1];
        const unsigned long long k1 = ((unsigned long long)wk[s & 1][1][0] << 32) | wk[s & 1][1][1];
        const unsigned long long k2 = ((unsigned long long)wk[s & 1][2][0] << 32) | wk[s & 1][2][1];
        const unsigned long long k3 = ((unsigned long long)wk[s & 1][3][0] << 32) | wk[s & 1][3][1];
        const unsigned long long ka = k0 > k1 ? k0 : k1;
        const unsigned long long kb = k2 > k3 ? k2 : k3;
        const unsigned long long kw = ka > kb ? ka : kb;

        const int wi = (int)(~(unsigned)kw);
        const float4 cc = pts4[wi];
        cx = cc.x; cy = cc.y; cz = cc.z;
    }

    __syncthreads();
    float* ob = out_xyz + (size_t)b * NS * 3;
#pragma unroll
    for (int r2 = 0; r2 < 12; ++r2) {
        const int f = t + r2 * 256;
        const int i = f / 3;
        const int cmp = f - 3 * i;
        const float v = (cmp == 0) ? hx[i] : ((cmp == 1) ? hy[i] : hz[i]);
        ob[f] = v;
    }
}

// ---------------------------------------------------------------------------
// KNN: unchanged from R10 (verified exact, DPP argmin).
// ---------------------------------------------------------------------------
#define KNN_INF 3.0e38f

__global__ __launch_bounds__(1024) void knn_kernel(const float* __restrict__ xyz,
                                                   const float* __restrict__ newxyz,
                                                   unsigned short* __restrict__ knn) {
    __shared__ float4 pts[NPTS];

    const int b = blockIdx.x >> 6;
    const int t = threadIdx.x;
    const float* xb = xyz + (size_t)b * NPTS * 3;
    for (int i = t; i < NPTS; i += 1024) {
        const float x = xb[3 * i], y = xb[3 * i + 1], z = xb[3 * i + 2];
        const float ps = __fadd_rn(__fadd_rn(__fmul_rn(x, x), __fmul_rn(y, y)), __fmul_rn(z, z));
        pts[i] = make_float4(x, y, z, ps);
    }
    __syncthreads();

    const int lane = t & 63;
    const int wv = t >> 6;
    const int s = ((blockIdx.x & 63) << 4) + wv;

    const float* q = newxyz + ((size_t)b * NS + s) * 3;
    const float qx = q[0], qy = q[1], qz = q[2];
    const float qs = __fadd_rn(__fadd_rn(__fmul_rn(qx, qx), __fmul_rn(qy, qy)), __fmul_rn(qz, qz));

    float v0 = KNN_INF, v1 = KNN_INF, v2 = KNN_INF, v3 = KNN_INF;
    int i0 = 0, i1 = 0, i2 = 0, i3 = 0;
    unsigned long long rem = 0ull;

#pragma unroll 4
    for (int j = 0; j < 64; ++j) {
        const float4 p = pts[j * 64 + lane];
        const float dot = __fmaf_rn(qz, p.z, __fmaf_rn(qy, p.y, __fmul_rn(qx, p.x)));
        const float d = __fadd_rn(__fsub_rn(qs, __fadd_rn(dot, dot)), p.w);
        const int gi = j * 64 + lane;
        const bool c0 = d < v0, c1 = d < v1, c2 = d < v2, c3 = d < v3;
        v3 = c3 ? (c2 ? v2 : d) : v3;  i3 = c3 ? (c2 ? i2 : gi) : i3;
        v2 = c2 ? (c1 ? v1 : d) : v2;  i2 = c2 ? (c1 ? i1 : gi) : i2;
        v1 = c1 ? (c0 ? v0 : d) : v1;  i1 = c1 ? (c0 ? i0 : gi) : i1;
        v0 = c0 ? d : v0;              i0 = c0 ? gi : i0;
    }

    int kidx = 0;
#pragma unroll 1
    for (int r = 0; r < NK; ++r) {
        float rv = v0;
        { const float o = __int_as_float(DPP_ROR_I(__float_as_int(rv), 1)); rv = fminf(rv, o); }
        { const float o = __int_as_float(DPP_ROR_I(__float_as_int(rv), 2)); rv = fminf(rv, o); }
        { const float o = __int_as_float(DPP_ROR_I(__float_as_int(rv), 4)); rv = fminf(rv, o); }
        { const float o = __int_as_float(DPP_ROR_I(__float_as_int(rv), 8)); rv = fminf(rv, o); }
        const float q0v = __int_as_float(__builtin_amdgcn_readlane(__float_as_int(rv), 0));
        const float q1v = __int_as_float(__builtin_amdgcn_readlane(__float_as_int(rv), 16));
        const float q2v = __int_as_float(__builtin_amdgcn_readlane(__float_as_int(rv), 32));
        const float q3v = __int_as_float(__builtin_amdgcn_readlane(__float_as_int(rv), 48));
        const float wm = fminf(fminf(q0v, q1v), fminf(q2v, q3v));

        unsigned cand = (v0 == wm) ? (unsigned)i0 : 0x7FFFFFFFu;
        { const unsigned o = (unsigned)DPP_ROR_I(cand, 1); cand = o < cand ? o : cand; }
        { const unsigned o = (unsigned)DPP_ROR_I(cand, 2); cand = o < cand ? o : cand; }
        { const unsigned o = (unsigned)DPP_ROR_I(cand, 4); cand = o < cand ? o : cand; }
        { const unsigned o = (unsigned)DPP_ROR_I(cand, 8); cand = o < cand ? o : cand; }
        const unsigned c0r = (unsigned)__builtin_amdgcn_readlane((int)cand, 0);
        const unsigned c1r = (unsigned)__builtin_amdgcn_readlane((int)cand, 16);
        const unsigned c2r = (unsigned)__builtin_amdgcn_readlane((int)cand, 32);
        const unsigned c3r = (unsigned)__builtin_amdgcn_readlane((int)cand, 48);
        const unsigned ca = c0r < c1r ? c0r : c1r;
        const unsigned cb = c2r < c3r ? c2r : c3r;
        const int bi = (int)(ca < cb ? ca : cb);

        if (lane == r) kidx = bi;
        if ((bi & 63) == lane) {
            v0 = v1; i0 = i1;
            v1 = v2; i1 = i2;
            v2 = v3; i2 = i3;
            v3 = KNN_INF;
            rem |= 1ull << (bi >> 6);
            if (v0 >= 1e37f) {
                v0 = v1 = v2 = v3 = KNN_INF;
#pragma unroll 1
                for (int j = 0; j < 64; ++j) {
                    if (!((rem >> j) & 1ull)) {
                        const float4 p = pts[j * 64 + lane];
                        const float dot = __fmaf_rn(qz, p.z, __fmaf_rn(qy, p.y, __fmul_rn(qx, p.x)));
                        const float d = __fadd_rn(__fsub_rn(qs, __fadd_rn(dot, dot)), p.w);
                        const int gi = j * 64 + lane;
                        const bool c0 = d < v0, c1 = d < v1, c2 = d < v2, c3 = d < v3;
                        v3 = c3 ? (c2 ? v2 : d) : v3;  i3 = c3 ? (c2 ? i2 : gi) : i3;
                        v2 = c2 ? (c1 ? v1 : d) : v2;  i2 = c2 ? (c1 ? i1 : gi) : i2;
                        v1 = c1 ? (c0 ? v0 : d) : v1;  i1 = c1 ? (c0 ? i0 : gi) : i1;
                        v0 = c0 ? d : v0;              i0 = c0 ? gi : i0;
                    }
                }
            }
        }
    }

    if (lane < NK) knn[(((size_t)b * NS + s) << 5) + lane] = (unsigned short)kidx;
}

// ---------------------------------------------------------------------------
// MLP via split-bf16 MFMA (hi/lo decomposition, fp32 accumulate).
// Block = 64 rows (2 groups), 4 waves. Feature order permuted to
// [points(64), dxyz(3), 0-pad] with W rows permuted to match.
// A-fragments: one ds_read_b128 from hi/lo LDS arrays.
// B-fragments: per-wave registers built from global weights.
// Maxpool over K=32 done in-register (relu after max == max after relu).
// ---------------------------------------------------------------------------
__global__ __launch_bounds__(256) void mlp_kernel(const float* __restrict__ xyz,
                                                  const float* __restrict__ points,
                                                  const float* __restrict__ newxyz,
                                                  const unsigned short* __restrict__ knn,
                                                  const float* __restrict__ w0, const float* __restrict__ b0,
                                                  const float* __restrict__ w1, const float* __restrict__ b1,
                                                  const float* __restrict__ w2, const float* __restrict__ b2,
                                                  float* __restrict__ out) {
    __shared__ unsigned aHi[64 * 52], aLo[64 * 52];   // L1 input (stride 52 u32); reused as L3 input (stride 36)
    __shared__ unsigned bHi[64 * 36], bLo[64 * 36];   // L2 input (stride 36 u32 = 72 ushort)
    __shared__ int sI[64];

    const int t = threadIdx.x;
    const int lane = t & 63;
    const int wv = t >> 6;
    const int g0 = blockIdx.x * 2;
    const int bb = g0 >> 10;

    if (t < 64) sI[t] = knn[((size_t)g0 + (t >> 5)) * 32 + (t & 31)];
    __syncthreads();

    // gather points -> hi/lo bf16 pairs (k = 0..63)
#pragma unroll
    for (int j = 0; j < 4; ++j) {
        const int id = j * 256 + t;
        const int row = id >> 4, qq = id & 15;
        const float4 p = *(const float4*)(points + (((size_t)bb * NPTS + sI[row]) << 6) + qq * 4);
        aHi[row * 52 + qq * 2]     = pkhi(p.x, p.y);
        aHi[row * 52 + qq * 2 + 1] = pkhi(p.z, p.w);
        aLo[row * 52 + qq * 2]     = pklo(p.x, p.y);
        aLo[row * 52 + qq * 2 + 1] = pklo(p.z, p.w);
    }
    // dxyz (k = 64..66), zero at k = 67
    if (t < 64) {
        const int row = t;
        const int idx = sI[row];
        const int gg = g0 + (row >> 5);
        const float* pp = xyz + ((size_t)bb * NPTS + idx) * 3;
        const float* qn = newxyz + (size_t)gg * 3;
        const float dx = pp[0] - qn[0];
        const float dy = pp[1] - qn[1];
        const float dz = pp[2] - qn[2];
        aHi[row * 52 + 32] = pkhi(dx, dy);
        aHi[row * 52 + 33] = pkhi(dz, 0.0f);
        aLo[row * 52 + 32] = pklo(dx, dy);
        aLo[row * 52 + 33] = pklo(dz, 0.0f);
    }
    // zero pad k = 68..99
#pragma unroll
    for (int j = 0; j < 4; ++j) {
        const int id = j * 256 + t;
        const int row = id >> 4, c = 34 + (id & 15);
        aHi[row * 52 + c] = 0u;
        aLo[row * 52 + c] = 0u;
    }

    // ---- W0 fragments (wave wv owns N-tile wv), K = 96 (3 k-tiles), permuted rows
    const int col0 = (wv << 4) + (lane & 15);
    const int kb = (lane >> 4) << 3;
    bf16x8 w0h[3], w0l[3];
#pragma unroll
    for (int kt = 0; kt < 3; ++kt) {
#pragma unroll
        for (int j = 0; j < 8; ++j) {
            const int k = kt * 32 + kb + j;
            const int worig = (k < 64) ? (k + 3) : ((k < 67) ? (k - 64) : -1);
            const float v = (worig >= 0) ? w0[worig * 64 + col0] : 0.0f;
            const unsigned short h = f2bf(v);
            w0h[kt][j] = (short)h;
            w0l[kt][j] = (short)f2bf(v - bf2f(h));
        }
    }
    const float bias0 = b0[col0];
    __syncthreads();

    // ---- Layer 1: 96(67) -> 64
#pragma unroll
    for (int mt = 0; mt < 4; ++mt) {
        f32x4 acc = { bias0, bias0, bias0, bias0 };
#pragma unroll
        for (int kt = 0; kt < 3; ++kt) {
            const int base = (mt * 16 + (lane & 15)) * 52 + kt * 16 + ((lane >> 4) << 2);
            const bf16x8 ah = *(const bf16x8*)&aHi[base];
            const bf16x8 al = *(const bf16x8*)&aLo[base];
            acc = MFMA16(ah, w0h[kt], acc);
            acc = MFMA16(al, w0h[kt], acc);
            acc = MFMA16(ah, w0l[kt], acc);
        }
#pragma unroll
        for (int r = 0; r < 4; ++r) {
            const float v = fmaxf(acc[r], 0.0f);
            const int row = mt * 16 + ((lane >> 4) << 2) + r;
            const unsigned short h = f2bf(v);
            ((unsigned short*)bHi)[row * 72 + col0] = h;
            ((unsigned short*)bLo)[row * 72 + col0] = f2bf(v - bf2f(h));
        }
    }

    // ---- W1 fragments, K = 64 (2 k-tiles)
    bf16x8 w1h[2], w1l[2];
#pragma unroll
    for (int kt = 0; kt < 2; ++kt) {
#pragma unroll
        for (int j = 0; j < 8; ++j) {
            const int k = kt * 32 + kb + j;
            const float v = w1[k * 64 + col0];
            const unsigned short h = f2bf(v);
            w1h[kt][j] = (short)h;
            w1l[kt][j] = (short)f2bf(v - bf2f(h));
        }
    }
    const float bias1 = b1[col0];
    __syncthreads();

    // ---- Layer 2: 64 -> 64
#pragma unroll
    for (int mt = 0; mt < 4; ++mt) {
        f32x4 acc = { bias1, bias1, bias1, bias1 };
#pragma unroll
        for (int kt = 0; kt < 2; ++kt) {
            const int base = (mt * 16 + (lane & 15)) * 36 + kt * 16 + ((lane >> 4) << 2);
            const bf16x8 ah = *(const bf16x8*)&bHi[base];
            const bf16x8 al = *(const bf16x8*)&bLo[base];
            acc = MFMA16(ah, w1h[kt], acc);
            acc = MFMA16(al, w1h[kt], acc);
            acc = MFMA16(ah, w1l[kt], acc);
        }
#pragma unroll
        for (int r = 0; r < 4; ++r) {
            const float v = fmaxf(acc[r], 0.0f);
            const int row = mt * 16 + ((lane >> 4) << 2) + r;
            const unsigned short h = f2bf(v);
            ((unsigned short*)aHi)[row * 72 + col0] = h;
            ((unsigned short*)aLo)[row * 72 + col0] = f2bf(v - bf2f(h));
        }
    }

    // ---- W2 fragments: wave owns N-tiles wv and wv+4
    const int colB = ((wv + 4) << 4) + (lane & 15);
    bf16x8 w2ha[2], w2la[2], w2hb[2], w2lb[2];
#pragma unroll
    for (int kt = 0; kt < 2; ++kt) {
#pragma unroll
        for (int j = 0; j < 8; ++j) {
            const int k = kt * 32 + kb + j;
            float v = w2[k * 128 + col0];
            unsigned short h = f2bf(v);
            w2ha[kt][j] = (short)h;
            w2la[kt][j] = (short)f2bf(v - bf2f(h));
            v = w2[k * 128 + colB];
            h = f2bf(v);
            w2hb[kt][j] = (short)h;
            w2lb[kt][j] = (short)f2bf(v - bf2f(h));
        }
    }
    const float bias2a = b2[col0];
    const float bias2b = b2[colB];
    __syncthreads();

    // ---- Layer 3: 64 -> 128, fused in-register maxpool over each group's 32 rows
#pragma unroll
    for (int gj = 0; gj < 2; ++gj) {
        f32x4 aA[2], aB[2];
#pragma unroll
        for (int hh = 0; hh < 2; ++hh) {
            const int mt = gj * 2 + hh;
            f32x4 accA = { bias2a, bias2a, bias2a, bias2a };
            f32x4 accB = { bias2b, bias2b, bias2b, bias2b };
#pragma unroll
            for (int kt = 0; kt < 2; ++kt) {
                const int base = (mt * 16 + (lane & 15)) * 36 + kt * 16 + ((lane >> 4) << 2);
                const bf16x8 ah = *(const bf16x8*)&aHi[base];
                const bf16x8 al = *(const bf16x8*)&aLo[base];
                accA = MFMA16(ah, w2ha[kt], accA);
                accA = MFMA16(al, w2ha[kt], accA);
                accA = MFMA16(ah, w2la[kt], accA);
                accB = MFMA16(ah, w2hb[kt], accB);
                accB = MFMA16(al, w2hb[kt], accB);
                accB = MFMA16(ah, w2lb[kt], accB);
            }
            aA[hh] = accA;
            aB[hh] = accB;
        }
        float mA = max3f(max3f(aA[0][0], aA[0][1], aA[0][2]),
                         max3f(aA[0][3], aA[1][0], aA[1][1]),
                         fmaxf(aA[1][2], aA[1][3]));
        float mB = max3f(max3f(aB[0][0], aB[0][1], aB[0][2]),
                         max3f(aB[0][3], aB[1][0], aB[1][1]),
                         fmaxf(aB[1][2], aB[1][3]));
        mA = fmaxf(mA, __shfl_xor(mA, 16));
        mA = fmaxf(mA, __shfl_xor(mA, 32));
        mB = fmaxf(mB, __shfl_xor(mB, 16));
        mB = fmaxf(mB, __shfl_xor(mB, 32));
        mA = fmaxf(mA, 0.0f);   // relu after max == max of relu'd values
        mB = fmaxf(mB, 0.0f);
        float* op = out + (size_t)(g0 + gj) * 128;
        if (lane < 16) {
            op[(wv << 4) + lane] = mA;
            op[((wv + 4) << 4) + lane] = mB;
        }
    }
}

extern "C" void kernel_launch(void* const* d_in, const int* in_sizes, int n_in,
                              void* d_out, int out_size, void* d_ws, size_t ws_size,
                              hipStream_t stream) {
    const float* xyz    = (const float*)d_in[0];
    const float* points = (const float*)d_in[1];
    const float* w0 = (const float*)d_in[2];
    const float* b0 = (const float*)d_in[3];
    const float* w1 = (const float*)d_in[4];
    const float* b1 = (const float*)d_in[5];
    const float* w2 = (const float*)d_in[6];
    const float* b2 = (const float*)d_in[7];

    float* out = (float*)d_out;
    float* newxyz = out;                          // (B, S, 3)
    float* newpts = out + (size_t)NB * NS * 3;    // (B, S, 128)
    unsigned short* knn = (unsigned short*)d_ws;  // (B, S, K) u16, 1 MB

    fps_kernel<<<NB, 256, 0, stream>>>(xyz, newxyz);
    knn_kernel<<<NB * (NS / 16), 1024, 0, stream>>>(xyz, newxyz, knn);
    mlp_kernel<<<(NB * NS) / 2, 256, 0, stream>>>(xyz, points, newxyz, knn,
                                                  w0, b0, w1, b1, w2, b2, newpts);
}